// Round 6
// baseline (151.324 us; speedup 1.0000x reference)
//
#include <hip/hip_runtime.h>
#include <math.h>

namespace {

constexpr int Bn = 64, Cn = 128, Tn = 512, Hn = 256;
constexpr int MR = 32;          // t-rows per block
constexpr int TB = Tn / MR;     // 16 -> grid 1024
constexpr int K1 = Cn * 9;      // 1152
constexpr int K2 = Hn * 9;      // 2304
constexpr int FC = 16;          // feats per k-chunk
constexpr int KC = 144;         // k per chunk = 9 j-slots * 16 feats
constexpr int KSS = 152;        // act row stride shorts (304B; slots 144..151 = trash pad)
constexpr int HS = 274;         // h1 row stride shorts (548B; odd dword stride -> conflict-free col reads)
constexpr int NCH1 = 8, NCH2 = 16;
constexpr float LN_EPS = 1e-5f;

typedef __attribute__((ext_vector_type(8))) short short8;
typedef __attribute__((ext_vector_type(16))) float f32x16;

// fp32 -> bf16 bits, round-to-nearest-even
__device__ __forceinline__ unsigned short f2bf(float f) {
  unsigned int u = __builtin_bit_cast(unsigned int, f);
  u = (u + 0x7fffu + ((u >> 16) & 1u)) >> 16;
  return (unsigned short)u;
}
__device__ __forceinline__ float bf2f(unsigned short u) {
  unsigned int v = (unsigned int)u << 16;
  return __builtin_bit_cast(float, v);
}

// Closed-form uniform cubic B-spline, grid g[j] = 0.4*(j-3) - 1.
// Writes silu at slot 128+feat and 4 nonzero bases at j*16+feat
// (out-of-range j diverted branchlessly to trash slots 144..151).
// Basis slots 0..127 must be pre-zeroed wave-locally.
__device__ __forceinline__ void act_store(float z,
                                          unsigned short* __restrict__ rowp,
                                          int feat) {
  const float e = __expf(-z);
  rowp[128 + feat] = f2bf(z * __builtin_amdgcn_rcpf(1.0f + e));
  const float p = z * 2.5f + 5.5f;
  const float fi = floorf(p);
  const int ib = (int)fi - 3;  // first nonzero j
  const float u = p - fi;
  const float u2 = u * u, u3 = u2 * u, tt = 1.0f - u;
  const float wv0 = tt * tt * tt * (1.0f / 6.0f);
  const float wv1 = (3.0f * u3 - 6.0f * u2 + 4.0f) * (1.0f / 6.0f);
  const float wv2 = (-3.0f * u3 + 3.0f * u2 + 3.0f * u + 1.0f) * (1.0f / 6.0f);
  const float wv3 = u3 * (1.0f / 6.0f);
  const float wv[4] = {wv0, wv1, wv2, wv3};
#pragma unroll
  for (int s = 0; s < 4; ++s) {
    const int j = ib + s;
    const int off = (j >= 0 && j <= 7) ? j * 16 + feat : 144 + (feat & 7);
    rowp[off] = f2bf(wv[s]);
  }
}

}  // namespace

// ---------------------------------------------------------------------------
// Prep: blk 0..255 pack weights bf16 (k = (feat>>4)*144 + j*16 + feat&15);
// blk 256..511 per-batch LN partial sums; blk 512..639 transpose ln_w/ln_b
// to bf16 [c][t] for coalesced act1 loads.
// ---------------------------------------------------------------------------
__global__ __launch_bounds__(256) void kan_prep(
    const float* __restrict__ U, const float* __restrict__ ln_w,
    const float* __restrict__ ln_b, const float* __restrict__ bw1,
    const float* __restrict__ sw1, const float* __restrict__ ss1,
    const float* __restrict__ bw2, const float* __restrict__ sw2,
    const float* __restrict__ ss2, unsigned short* __restrict__ W1p,
    unsigned short* __restrict__ W2p, unsigned short* __restrict__ lnwT,
    unsigned short* __restrict__ lnbT, float* __restrict__ stats) {
  __shared__ float red[2][4];
  const int blk = blockIdx.x;
  if (blk < 256) {
    int idx = blk * 256 + threadIdx.x;  // 0..65535
    if (idx < Hn * Cn) {
      const int h = idx >> 7, c = idx & 127;
      const float* spw = sw1 + ((size_t)h * Cn + c) * 8;
      const float sc = ss1[h * Cn + c];
      unsigned short* dst = W1p + (size_t)h * K1 + (c >> 4) * KC + (c & 15);
#pragma unroll
      for (int j = 0; j < 8; ++j) dst[j * 16] = f2bf(spw[j] * sc);
      dst[8 * 16] = f2bf(bw1[h * Cn + c]);
    } else {
      idx -= Hn * Cn;
      const int c = idx >> 8, h = idx & 255;
      const float* spw = sw2 + ((size_t)c * Hn + h) * 8;
      const float sc = ss2[c * Hn + h];
      unsigned short* dst = W2p + (size_t)c * K2 + (h >> 4) * KC + (h & 15);
#pragma unroll
      for (int j = 0; j < 8; ++j) dst[j * 16] = f2bf(spw[j] * sc);
      dst[8 * 16] = f2bf(bw2[c * Hn + h]);
    }
  } else if (blk < 512) {
    const int sblk = blk - 256;
    const int b = sblk >> 2, q = sblk & 3;
    const float4* p =
        (const float4*)(U + (size_t)b * (Cn * Tn) + q * (Cn * Tn / 4));
    float s = 0.f, s2 = 0.f;
#pragma unroll 4
    for (int i = threadIdx.x; i < (Cn * Tn / 4) / 4; i += 256) {
      const float4 v = p[i];
      s += v.x + v.y + v.z + v.w;
      s2 += v.x * v.x + v.y * v.y + v.z * v.z + v.w * v.w;
    }
#pragma unroll
    for (int off = 32; off > 0; off >>= 1) {
      s += __shfl_down(s, off);
      s2 += __shfl_down(s2, off);
    }
    if ((threadIdx.x & 63) == 0) {
      red[0][threadIdx.x >> 6] = s;
      red[1][threadIdx.x >> 6] = s2;
    }
    __syncthreads();
    if (threadIdx.x == 0) {
      stats[b * 8 + q * 2 + 0] = red[0][0] + red[0][1] + red[0][2] + red[0][3];
      stats[b * 8 + q * 2 + 1] = red[1][0] + red[1][1] + red[1][2] + red[1][3];
    }
  } else {
    const int bb = blk - 512;  // 0..127
    const float* src = (bb < 64) ? ln_w : ln_b;
    unsigned short* dst = (bb < 64) ? lnwT : lnbT;
    const int base = (bb & 63) * 1024;
#pragma unroll
    for (int e2 = 0; e2 < 4; ++e2) {
      const int i = base + (int)threadIdx.x + e2 * 256;  // = c*512 + t
      const int c = i >> 9, t = i & 511;
      dst[i] = f2bf(src[t * Cn + c]);
    }
  }
}

// ---------------------------------------------------------------------------
// Fused LN -> KAN1 -> KAN2 -> residual.
// 1024 blocks x 512 threads (8 waves), 32 t-rows/block, 37 KB LDS.
// Per chunk: [pinned load cluster (next weights + next act inputs)] ->
// [MFMA on current] -> [act VALU + store next] -> barrier.
// Layer 2: waves 0-3 produce act, waves 4-7 consume (MFMA, setprio).
// ---------------------------------------------------------------------------
__global__ __launch_bounds__(512, 4) void kan_fused(
    const float* __restrict__ U, const unsigned short* __restrict__ lnwT,
    const unsigned short* __restrict__ lnbT,
    const unsigned short* __restrict__ W1p,
    const unsigned short* __restrict__ W2p, const float* __restrict__ stats,
    float* __restrict__ out) {
  __shared__ unsigned short s_buf[2][MR * KSS];  // 2 x 9728 B
  __shared__ unsigned short s_h1[MR * HS];       // 17536 B

  const int tid = threadIdx.x;
  const int b = blockIdx.x >> 4;
  const int t0 = (blockIdx.x & 15) * MR;

  const float* sp = stats + b * 8;
  const float ssum = sp[0] + sp[2] + sp[4] + sp[6];
  const float ssq = sp[1] + sp[3] + sp[5] + sp[7];
  const float inv_n = 1.0f / (float)(Cn * Tn);
  const float mean = ssum * inv_n;
  const float rstd = rsqrtf(ssq * inv_n - mean * mean + LN_EPS);

  const int w = tid >> 6, l = tid & 63;
  const int ln31 = l & 31, hl = l >> 5;
  const int a_feat = tid >> 5;  // 0..15 (wave w -> feats 2w, 2w+1)
  const int a_row = tid & 31;   // lanes 0..31 -> consecutive t (coalesced)

  // Wave-local zero of the basis region (dwords j*8+w cover feats 2w,2w+1).
  auto zero1 = [&](unsigned short* nbuf) {
    unsigned int* zb = (unsigned int*)nbuf;
#pragma unroll
    for (int it = 0; it < 4; ++it) {
      const int e = l + it * 64;
      zb[(e & 31) * (KSS / 2) + (e >> 5) * 8 + w] = 0u;
    }
  };
  // Producer-wave zero (w<4): feats 4w..4w+3 -> dwords j*8 + 2w + {0,1}.
  auto zero2 = [&](unsigned short* nbuf) {
    unsigned int* zb = (unsigned int*)nbuf;
#pragma unroll
    for (int it = 0; it < 8; ++it) {
      const int e = l + it * 64;
      const int idx = e >> 5;  // 0..15
      zb[(e & 31) * (KSS / 2) + (idx >> 1) * 8 + 2 * w + (idx & 1)] = 0u;
    }
  };

  auto act1_load = [&](int chunk, float& uS, unsigned short& wS,
                       unsigned short& bS) {
    const int c = chunk * FC + a_feat;
    const int t = t0 + a_row;
    uS = U[((size_t)b * Cn + c) * Tn + t];
    wS = lnwT[c * Tn + t];
    bS = lnbT[c * Tn + t];
  };
  auto act1_fire = [&](unsigned short* nbuf, float uS, unsigned short wS,
                       unsigned short bS) {
    zero1(nbuf);
    const float z = (uS - mean) * rstd * bf2f(wS) + bf2f(bS);
    act_store(z, nbuf + a_row * KSS, a_feat);
  };
  // act2: producers only (tid < 256): feat = tid>>4, rows tid&15, +16
  auto act2_all = [&](int chunk, unsigned short* nbuf) {
    zero2(nbuf);
    const int pf = tid >> 4;
#pragma unroll
    for (int pp = 0; pp < 2; ++pp) {
      const int row = (l & 15) + pp * 16;
      const float z = bf2f(s_h1[row * HS + chunk * FC + pf]);
      act_store(z, nbuf + row * KSS, pf);
    }
  };

  // ==================== Layer 1: M=32, N=256, K=1152 ====================
  short8 breg0[9], breg1[9];
  const unsigned short* wb1 = W1p + (size_t)(w * 32 + ln31) * K1 + hl * 8;
#pragma unroll
  for (int ks = 0; ks < 9; ++ks) breg0[ks] = *(const short8*)(wb1 + ks * 16);
  {
    float uS;
    unsigned short wS, bS;
    act1_load(0, uS, wS, bS);
    act1_fire(s_buf[0], uS, wS, bS);
  }
  __syncthreads();

  f32x16 acc1 = {};
  auto l1step = [&](int kk, const unsigned short* CUR, unsigned short* NXT,
                    short8(&BC)[9], short8(&BN)[9]) {
    const bool more = kk < NCH1 - 1;
    float uS = 0.f;
    unsigned short wS = 0, bS = 0;
    if (more) {
#pragma unroll
      for (int ks = 0; ks < 9; ++ks)
        BN[ks] = *(const short8*)(wb1 + (kk + 1) * KC + ks * 16);
      act1_load(kk + 1, uS, wS, bS);
    }
    __builtin_amdgcn_sched_barrier(0);  // pin prefetch cluster above MFMA
    const unsigned short* ap = CUR + ln31 * KSS + hl * 8;
#pragma unroll
    for (int ks = 0; ks < 9; ++ks) {
      const short8 a = *(const short8*)(ap + ks * 16);
      acc1 = __builtin_amdgcn_mfma_f32_32x32x16_bf16(a, BC[ks], acc1, 0, 0, 0);
    }
    if (more) act1_fire(NXT, uS, wS, bS);
    __syncthreads();
  };
  for (int k = 0; k < NCH1; k += 2) {
    l1step(k, s_buf[0], s_buf[1], breg0, breg1);
    l1step(k + 1, s_buf[1], s_buf[0], breg1, breg0);
  }

  // ---- transition: consumers prefetch layer-2 chunk-0 weights first ----
  const unsigned short* wb2 = W2p + (size_t)((w & 3) * 32 + ln31) * K2 + hl * 8;
  if (w >= 4) {
#pragma unroll
    for (int ks = 0; ks < 9; ++ks) breg0[ks] = *(const short8*)(wb2 + ks * 16);
  }
  // h1 -> LDS bf16: C layout col=lane&31, row=(r&3)+8*(r>>2)+4*hl
#pragma unroll
  for (int r = 0; r < 16; ++r) {
    const int row = 4 * hl + (r & 3) + 8 * (r >> 2);
    s_h1[row * HS + w * 32 + ln31] = f2bf(acc1[r]);
  }
  __syncthreads();
  if (w < 4) act2_all(0, s_buf[0]);
  __syncthreads();

  // ==================== Layer 2: M=32, N=128, K=2304 ====================
  // waves 0-3: producers (act); waves 4-7: consumers (cols (w&3)*32+ln31)
  f32x16 acc2 = {};
  auto l2step = [&](int kk, const unsigned short* CUR, unsigned short* NXT,
                    short8(&BC)[9], short8(&BN)[9]) {
    const bool more = kk < NCH2 - 1;
    if (w >= 4) {
      if (more) {
#pragma unroll
        for (int ks = 0; ks < 9; ++ks)
          BN[ks] = *(const short8*)(wb2 + (kk + 1) * KC + ks * 16);
      }
      __builtin_amdgcn_sched_barrier(0);
      const unsigned short* ap = CUR + ln31 * KSS + hl * 8;
      __builtin_amdgcn_s_setprio(1);
#pragma unroll
      for (int ks = 0; ks < 9; ++ks) {
        const short8 a = *(const short8*)(ap + ks * 16);
        acc2 =
            __builtin_amdgcn_mfma_f32_32x32x16_bf16(a, BC[ks], acc2, 0, 0, 0);
      }
      __builtin_amdgcn_s_setprio(0);
    } else {
      if (more) act2_all(kk + 1, NXT);
    }
    __syncthreads();
  };
  for (int k = 0; k < NCH2; k += 2) {
    l2step(k, s_buf[0], s_buf[1], breg0, breg1);
    l2step(k + 1, s_buf[1], s_buf[0], breg1, breg0);
  }

  // ==================== Epilogue: residual + store (consumers) ============
  if (w >= 4) {
    const int c = (w & 3) * 32 + ln31;
#pragma unroll
    for (int g = 0; g < 4; ++g) {
      const int tb = t0 + 4 * hl + 8 * g;
      const size_t base = ((size_t)b * Cn + c) * Tn + tb;
      const float4 uin = *(const float4*)(U + base);
      float4 o;
      o.x = uin.x + acc2[g * 4 + 0];
      o.y = uin.y + acc2[g * 4 + 1];
      o.z = uin.z + acc2[g * 4 + 2];
      o.w = uin.w + acc2[g * 4 + 3];
      *(float4*)(out + base) = o;
    }
  }
}

extern "C" void kernel_launch(void* const* d_in, const int* in_sizes, int n_in,
                              void* d_out, int out_size, void* d_ws,
                              size_t ws_size, hipStream_t stream) {
  const float* U = (const float*)d_in[0];
  const float* ln_w = (const float*)d_in[1];
  const float* ln_b = (const float*)d_in[2];
  const float* bw1 = (const float*)d_in[3];
  const float* sw1 = (const float*)d_in[4];
  const float* ss1 = (const float*)d_in[5];
  const float* bw2 = (const float*)d_in[6];
  const float* sw2 = (const float*)d_in[7];
  const float* ss2 = (const float*)d_in[8];
  float* out = (float*)d_out;

  char* ws = (char*)d_ws;
  float* stats = (float*)ws;                              // 4 KB
  unsigned short* lnwT = (unsigned short*)(ws + 4096);    // 128 KB
  unsigned short* lnbT = lnwT + Cn * Tn;                  // 128 KB
  unsigned short* W1p = lnbT + Cn * Tn;                   // 576 KB
  unsigned short* W2p = W1p + (size_t)Hn * K1;            // 1.125 MB

  kan_prep<<<640, 256, 0, stream>>>(U, ln_w, ln_b, bw1, sw1, ss1, bw2, sw2,
                                    ss2, W1p, W2p, lnwT, lnbT, stats);
  kan_fused<<<Bn * TB, 512, 0, stream>>>(U, lnwT, lnbT, W1p, W2p, stats, out);
}